// Round 1
// 139.469 us; speedup vs baseline: 1.0476x; 1.0476x over previous
//
#include <hip/hip_runtime.h>

// FAVOR+ causal linear attention, fp32 I/O, bf16 MFMA chunked-GEMM form.
// B=2, L=4096, H=8, D=64, M=128, chunks C=64 x T=64.
// Restructured 3-phase:
//   k1: Qf,Kf = relu(ratio*X P^T)+eps; cs = (V^T Kf, colsum Kf);
//       S = mask(Qf Kf^T); num2 = S V (f32, [t][d]); rs = rowsum(S).
//       Kf never hits global. Qf staged via LDS -> 1KB/wave coalesced stores.
//       cs/num2 written via swapped-operand MFMA (packed 8B/16B stores).
//   k2: exclusive bf16 prefix over chunks per (b,h); width-1 threads
//       (520 blocks), full 64-load register prefetch.
//   k3: LDS-free: num1 = Qf*KVpre in D[d][t] orientation (float4 out stores);
//       den = Qf.kspre + rs; out = (num1+num2)/den.

#define B_ 2
#define L_ 4096
#define H_ 8
#define D_ 64
#define M_ 128
#define BH_ 16
#define HD_ 512
#define LHD_ (L_*HD_)
#define C_ 64
#define T_ 64
#define RATIO 0.08838834764831845f
#define EPS 1e-3f

#define REC_CS 8320                    // shorts per cs record: 64*128 KVt + 128 ks
#define REC_F  8192                    // shorts per Qf record: 64*128
#define QF_OFF 8519680                 // shorts: 16*64*8320
#define N2_OFF 16908288                // shorts: QF_OFF + 16*64*8192 (f32 region)
#define RS_OFF 25296896                // shorts: N2_OFF + 2*4194304   (f32 region)

#define VT_S  72                       // LDS [d][t] row stride (shorts)
#define KFT_S 72                       // LDS [m][t] row stride (shorts)
#define TM_S  136                      // LDS [t][m] row stride (shorts, pad 8)

typedef __attribute__((ext_vector_type(8))) short bf16x8;
typedef __attribute__((ext_vector_type(4))) short bf16x4;
typedef __attribute__((ext_vector_type(4))) float f32x4;

__device__ __forceinline__ short f2bf(float f) {
  union { float f; unsigned u; } x; x.f = f;
  unsigned r = (x.u + 0x7fffu + ((x.u >> 16) & 1u)) >> 16;
  return (short)r;
}
__device__ __forceinline__ float bf2f(short s) {
  union { unsigned u; float f; } x; x.u = ((unsigned)(unsigned short)s) << 16;
  return x.f;
}
__device__ __forceinline__ bf16x8 load_cvt8(const float* p) {
  float4 a = *(const float4*)p;
  float4 b = *(const float4*)(p + 4);
  union { bf16x8 v; short s[8]; } u;
  u.s[0]=f2bf(a.x); u.s[1]=f2bf(a.y); u.s[2]=f2bf(a.z); u.s[3]=f2bf(a.w);
  u.s[4]=f2bf(b.x); u.s[5]=f2bf(b.y); u.s[6]=f2bf(b.z); u.s[7]=f2bf(b.w);
  return u.v;
}
#define MFMA(a,b,c) __builtin_amdgcn_mfma_f32_16x16x32_bf16((a),(b),(c),0,0,0)

// ---------------- k1: per-chunk everything except cross-chunk prefix --------
__global__ __launch_bounds__(256) void k1(
    const float* __restrict__ qq, const float* __restrict__ kk,
    const float* __restrict__ vv, const float* __restrict__ P,
    unsigned short* __restrict__ ws)
{
  __shared__ short Vt[64*VT_S];       // [d][t]
  __shared__ short Kft[128*KFT_S];    // [m][t]
  __shared__ short KfTM[64*TM_S];     // [t][m]
  __shared__ short QfTM[64*TM_S];     // [t][m]; reused as Sm after sync2

  const int tid = threadIdx.x, bid = blockIdx.x;
  const int bh = bid >> 6, c = bid & 63;
  const int b = bh >> 3, h = bh & 7;
  const int lane = tid & 63, w = tid >> 6, quad = lane >> 4, l15 = lane & 15;
  const size_t gbase = (size_t)b*LHD_ + (size_t)h*D_;
  const int t0 = c*T_;

  // stage Vt[d][t] (transpose)
  for (int fi = tid; fi < 64*16; fi += 256) {
    int t = fi >> 4, d4 = (fi & 15)*4;
    float4 v4 = *(const float4*)(vv + gbase + (size_t)(t0+t)*HD_ + d4);
    Vt[(d4+0)*VT_S + t] = f2bf(v4.x);
    Vt[(d4+1)*VT_S + t] = f2bf(v4.y);
    Vt[(d4+2)*VT_S + t] = f2bf(v4.z);
    Vt[(d4+3)*VT_S + t] = f2bf(v4.w);
  }

  // features, swapped operands: D[m][t] -> lane holds t=16w+l15, m=16ct+4q+reg
  const float* qrow = qq + gbase + (size_t)(t0 + 16*w + l15)*HD_;
  const float* krow = kk + gbase + (size_t)(t0 + 16*w + l15)*HD_;
  bf16x8 bq0 = load_cvt8(qrow + quad*8);
  bf16x8 bq1 = load_cvt8(qrow + 32 + quad*8);
  bf16x8 bk0 = load_cvt8(krow + quad*8);
  bf16x8 bk1 = load_cvt8(krow + 32 + quad*8);
  #pragma unroll
  for (int ct = 0; ct < 8; ++ct) {
    const float* prow = P + (ct*16 + l15)*64;
    bf16x8 ap0 = load_cvt8(prow + quad*8);
    bf16x8 ap1 = load_cvt8(prow + 32 + quad*8);
    f32x4 qa = {0.f,0.f,0.f,0.f}, ka = {0.f,0.f,0.f,0.f};
    qa = MFMA(ap0,bq0,qa); qa = MFMA(ap1,bq1,qa);
    ka = MFMA(ap0,bk0,ka); ka = MFMA(ap1,bk1,ka);
    union { bf16x4 v; short s[4]; } pq, pk;
    #pragma unroll
    for (int reg = 0; reg < 4; ++reg) {
      int m = 16*ct + 4*quad + reg;
      short qv = f2bf(fmaxf(qa[reg]*RATIO, 0.f) + EPS);
      short kv = f2bf(fmaxf(ka[reg]*RATIO, 0.f) + EPS);
      pq.s[reg] = qv; pk.s[reg] = kv;
      Kft[m*KFT_S + 16*w + l15] = kv;
    }
    *(bf16x4*)&QfTM[(16*w+l15)*TM_S + 16*ct + 4*quad] = pq.v;
    *(bf16x4*)&KfTM[(16*w+l15)*TM_S + 16*ct + 4*quad] = pk.v;
  }
  __syncthreads();  // sync1: Vt, Kft, KfTM, QfTM complete

  unsigned short* csb = ws + (size_t)(bh*C_+c)*REC_CS;
  unsigned short* qfb = ws + QF_OFF + (size_t)(bh*C_+c)*REC_F;

  // copy out Qf [t][m] dense; fully coalesced 16B stores (1KB/wave)
  {
    int tt = tid >> 4, mb = (tid & 15)*8;
    #pragma unroll
    for (int j = 0; j < 4; ++j) {
      bf16x8 v8 = *(const bf16x8*)&QfTM[(tt + 16*j)*TM_S + mb];
      *(bf16x8*)(qfb + (tt + 16*j)*128 + mb) = v8;
    }
  }
  // Qf A-frags (rows 16w+l15) for S
  bf16x8 qfr[4];
  #pragma unroll
  for (int ks2 = 0; ks2 < 4; ++ks2)
    qfr[ks2] = *(const bf16x8*)&QfTM[(16*w+l15)*TM_S + ks2*32 + quad*8];

  // ks[m] = sum_t Kf[t][m]
  if (tid < 128) {
    float s = 0.f;
    #pragma unroll
    for (int i = 0; i < 8; ++i) {
      bf16x8 r = *(const bf16x8*)&Kft[tid*KFT_S + 8*i];
      #pragma unroll
      for (int j = 0; j < 8; ++j) s += bf2f(r[j]);
    }
    csb[64*128 + tid] = (unsigned short)f2bf(s);
  }

  // KV^T: cs[d][m] = sum_t Kf[t][m] V[t][d]; swapped -> D[m][d], 8B stores
  {
    bf16x8 av0 = *(const bf16x8*)&Vt[(16*w + l15)*VT_S + quad*8];
    bf16x8 av1 = *(const bf16x8*)&Vt[(16*w + l15)*VT_S + 32 + quad*8];
    #pragma unroll
    for (int mt = 0; mt < 8; ++mt) {
      bf16x8 b0 = *(const bf16x8*)&Kft[(16*mt + l15)*KFT_S + quad*8];
      bf16x8 b1 = *(const bf16x8*)&Kft[(16*mt + l15)*KFT_S + 32 + quad*8];
      f32x4 acc = {0.f,0.f,0.f,0.f};
      acc = MFMA(b0, av0, acc);
      acc = MFMA(b1, av1, acc);
      union { bf16x4 v; short s[4]; } pc;
      #pragma unroll
      for (int reg = 0; reg < 4; ++reg) pc.s[reg] = f2bf(acc[reg]);
      *(bf16x4*)(csb + (16*w + l15)*128 + 16*mt + 4*quad) = pc.v;
    }
  }
  __syncthreads();  // sync2: all QfTM reads done -> reuse as Sm

  short* Sm = QfTM;

  // S = mask(Qf Kf^T): D[t][j], A=Qf regs, B=KfTM rows
  f32x4 sacc[4];
  #pragma unroll
  for (int jt = 0; jt < 4; ++jt) { f32x4 z = {0.f,0.f,0.f,0.f}; sacc[jt] = z; }
  #pragma unroll
  for (int ks2 = 0; ks2 < 4; ++ks2) {
    #pragma unroll
    for (int jt = 0; jt < 4; ++jt) {
      bf16x8 bb = *(const bf16x8*)&KfTM[(16*jt + l15)*TM_S + ks2*32 + quad*8];
      sacc[jt] = MFMA(qfr[ks2], bb, sacc[jt]);
    }
  }
  float rs[4] = {0.f,0.f,0.f,0.f};
  #pragma unroll
  for (int jt = 0; jt < 4; ++jt)
    #pragma unroll
    for (int reg = 0; reg < 4; ++reg) {
      int row = 16*w + 4*quad + reg;
      int j = l15 + 16*jt;
      float val = (j <= row) ? sacc[jt][reg] : 0.f;
      rs[reg] += val;
      Sm[row*TM_S + j] = f2bf(val);
    }
  #pragma unroll
  for (int reg = 0; reg < 4; ++reg) {
    rs[reg] += __shfl_xor(rs[reg], 1);
    rs[reg] += __shfl_xor(rs[reg], 2);
    rs[reg] += __shfl_xor(rs[reg], 4);
    rs[reg] += __shfl_xor(rs[reg], 8);
  }
  float* rsg = (float*)(ws + RS_OFF);
  if (l15 < 4) {
    float v = (l15==0) ? rs[0] : (l15==1) ? rs[1] : (l15==2) ? rs[2] : rs[3];
    rsg[bh*L_ + t0 + 16*w + 4*quad + l15] = v;
  }

  // num2[t][d] = S V as D[d][t]: A=Vt rows d, B=Sm rows t (same-wave rows)
  float* n2 = (float*)(ws + N2_OFF);
  f32x4 nacc[4];
  #pragma unroll
  for (int ct = 0; ct < 4; ++ct) { f32x4 z = {0.f,0.f,0.f,0.f}; nacc[ct] = z; }
  #pragma unroll
  for (int kss = 0; kss < 2; ++kss) {
    bf16x8 sb = *(const bf16x8*)&Sm[(16*w + l15)*TM_S + kss*32 + quad*8];
    #pragma unroll
    for (int ct = 0; ct < 4; ++ct) {
      bf16x8 a = *(const bf16x8*)&Vt[(16*ct + l15)*VT_S + kss*32 + quad*8];
      nacc[ct] = MFMA(a, sb, nacc[ct]);
    }
  }
  const int tg = t0 + 16*w + l15;
  #pragma unroll
  for (int ct = 0; ct < 4; ++ct) {
    float4 o;
    o.x = nacc[ct][0]; o.y = nacc[ct][1]; o.z = nacc[ct][2]; o.w = nacc[ct][3];
    *(float4*)(n2 + gbase + (size_t)tg*HD_ + 16*ct + 4*quad) = o;
  }
}

// ---------------- k2: bf16 exclusive prefix, width-1, full prefetch ---------
__global__ __launch_bounds__(256) void k2(unsigned short* __restrict__ ws)
{
  const int gid = blockIdx.x*256 + threadIdx.x;   // 520*256 = 16*8320 exactly
  const int bh = gid / REC_CS, e = gid % REC_CS;
  unsigned short* base = ws + (size_t)bh*C_*REC_CS + e;
  short v[64];
  #pragma unroll
  for (int c2 = 0; c2 < 64; ++c2) v[c2] = (short)base[(size_t)c2*REC_CS];
  float run = 0.f;
  #pragma unroll
  for (int c2 = 0; c2 < 64; ++c2) {
    base[(size_t)c2*REC_CS] = (unsigned short)f2bf(run);
    run += bf2f(v[c2]);
  }
}

// ---------------- k3: num1 + combine, LDS-free, float4 stores ---------------
__global__ __launch_bounds__(256) void k3(
    const unsigned short* __restrict__ ws, float* __restrict__ out)
{
  const int tid = threadIdx.x, bid = blockIdx.x;
  const int bh = bid >> 6, c = bid & 63;
  const int b = bh >> 3, h = bh & 7;
  const int lane = tid & 63, w = tid >> 6, quad = lane >> 4, l15 = lane & 15;
  const size_t gbase = (size_t)b*LHD_ + (size_t)h*D_;
  const int t0 = c*T_;
  const unsigned short* csb = ws + (size_t)(bh*C_+c)*REC_CS;
  const unsigned short* qfb = ws + QF_OFF + (size_t)(bh*C_+c)*REC_F;
  const float* n2 = (const float*)(ws + N2_OFF);
  const float* rsg = (const float*)(ws + RS_OFF);

  // Qf B-frags (rows t=16w+l15) + prefixed ks frags
  bf16x8 qfB[4], ksf[4];
  #pragma unroll
  for (int ks2 = 0; ks2 < 4; ++ks2) {
    qfB[ks2] = *(const bf16x8*)(qfb + (16*w + l15)*128 + ks2*32 + quad*8);
    ksf[ks2] = *(const bf16x8*)(csb + 64*128 + ks2*32 + quad*8);
  }
  // den1 = Qf . ks_prefix (per-lane partial over 32 m, reduce across quads)
  float dp = 0.f;
  #pragma unroll
  for (int ks2 = 0; ks2 < 4; ++ks2)
    #pragma unroll
    for (int j = 0; j < 8; ++j) dp += bf2f(qfB[ks2][j]) * bf2f(ksf[ks2][j]);
  dp += __shfl_xor(dp, 16);
  dp += __shfl_xor(dp, 32);

  const int tg = t0 + 16*w + l15;
  float rsv = rsg[bh*L_ + tg];
  float inv = 1.f / (dp + rsv);

  // num1 = Qf * KVpre as D[d][t]: A=cs rows d, B=Qf rows t
  f32x4 nacc[4];
  #pragma unroll
  for (int ct = 0; ct < 4; ++ct) { f32x4 z = {0.f,0.f,0.f,0.f}; nacc[ct] = z; }
  #pragma unroll
  for (int ks2 = 0; ks2 < 4; ++ks2) {
    #pragma unroll
    for (int ct = 0; ct < 4; ++ct) {
      bf16x8 a = *(const bf16x8*)(csb + (16*ct + l15)*128 + ks2*32 + quad*8);
      nacc[ct] = MFMA(a, qfB[ks2], nacc[ct]);
    }
  }
  #pragma unroll
  for (int ct = 0; ct < 4; ++ct) {
    float4 nv = *(const float4*)(n2 + gbase + (size_t)tg*HD_ + 16*ct + 4*quad);
    float4 o;
    o.x = (nacc[ct][0] + nv.x) * inv;
    o.y = (nacc[ct][1] + nv.y) * inv;
    o.z = (nacc[ct][2] + nv.z) * inv;
    o.w = (nacc[ct][3] + nv.w) * inv;
    *(float4*)(out + gbase + (size_t)tg*HD_ + 16*ct + 4*quad) = o;
  }
}

extern "C" void kernel_launch(void* const* d_in, const int* in_sizes, int n_in,
                              void* d_out, int out_size, void* d_ws, size_t ws_size,
                              hipStream_t stream) {
  const float* q = (const float*)d_in[0];
  const float* k = (const float*)d_in[1];
  const float* v = (const float*)d_in[2];
  const float* P = (const float*)d_in[3];
  float* out = (float*)d_out;
  unsigned short* ws = (unsigned short*)d_ws;  // needs ~50.9 MB

  dim3 blk(256);
  k1<<<dim3(BH_*C_), blk, 0, stream>>>(q, k, v, P, ws);
  k2<<<dim3(520), blk, 0, stream>>>(ws);
  k3<<<dim3(BH_*C_), blk, 0, stream>>>(ws, out);
}

// Round 2
// 133.026 us; speedup vs baseline: 1.0983x; 1.0484x over previous
//
#include <hip/hip_runtime.h>

// FAVOR+ causal linear attention, fp32 I/O, bf16 MFMA chunked-GEMM form.
// B=2, L=4096, H=8, D=64, M=128, chunks C=64 x T=64.
// 4-phase:
//   k0: P fp32 -> bf16 once (removes 384 redundant f2bf ops/thread from k1,
//       which was re-converting all of P per block -> VALU-chain bound).
//   k1: Qf,Kf = relu(ratio*X P^T)+eps; cs = (V^T Kf, colsum Kf);
//       S = mask(Qf Kf^T); num2 = S V (f32, [t][d]); rs = rowsum(S).
//       Kf never hits global. Qf staged via LDS -> coalesced 16B stores.
//   k2: exclusive bf16 prefix over chunks per (b,h); width-1 threads,
//       full 64-load register prefetch.
//   k3: LDS-free: num1 = Qf*KVpre in D[d][t] orientation (float4 out stores);
//       den = Qf.kspre + rs; out = (num1+num2)/den. n2 loads hoisted ahead
//       of the MFMA loop to overlap L3 latency.

#define B_ 2
#define L_ 4096
#define H_ 8
#define D_ 64
#define M_ 128
#define BH_ 16
#define HD_ 512
#define LHD_ (L_*HD_)
#define C_ 64
#define T_ 64
#define RATIO 0.08838834764831845f
#define EPS 1e-3f

#define REC_CS 8320                    // shorts per cs record: 64*128 KVt + 128 ks
#define REC_F  8192                    // shorts per Qf record: 64*128
#define QF_OFF 8519680                 // shorts: 16*64*8320
#define N2_OFF 16908288                // shorts: QF_OFF + 16*64*8192 (f32 region)
#define RS_OFF 25296896                // shorts: N2_OFF + 2*4194304   (f32 region)
#define P_OFF  25427968                // shorts: RS_OFF + 131072; P bf16 [m][d]

#define VT_S  72                       // LDS [d][t] row stride (shorts)
#define KFT_S 72                       // LDS [m][t] row stride (shorts)
#define TM_S  136                      // LDS [t][m] row stride (shorts, pad 8)

typedef __attribute__((ext_vector_type(8))) short bf16x8;
typedef __attribute__((ext_vector_type(4))) short bf16x4;
typedef __attribute__((ext_vector_type(4))) float f32x4;

__device__ __forceinline__ short f2bf(float f) {
  union { float f; unsigned u; } x; x.f = f;
  unsigned r = (x.u + 0x7fffu + ((x.u >> 16) & 1u)) >> 16;
  return (short)r;
}
__device__ __forceinline__ float bf2f(short s) {
  union { unsigned u; float f; } x; x.u = ((unsigned)(unsigned short)s) << 16;
  return x.f;
}
__device__ __forceinline__ bf16x8 load_cvt8(const float* p) {
  float4 a = *(const float4*)p;
  float4 b = *(const float4*)(p + 4);
  union { bf16x8 v; short s[8]; } u;
  u.s[0]=f2bf(a.x); u.s[1]=f2bf(a.y); u.s[2]=f2bf(a.z); u.s[3]=f2bf(a.w);
  u.s[4]=f2bf(b.x); u.s[5]=f2bf(b.y); u.s[6]=f2bf(b.z); u.s[7]=f2bf(b.w);
  return u.v;
}
#define MFMA(a,b,c) __builtin_amdgcn_mfma_f32_16x16x32_bf16((a),(b),(c),0,0,0)

// ---------------- k0: P -> bf16 once ----------------------------------------
__global__ __launch_bounds__(256) void k0(
    const float* __restrict__ P, unsigned short* __restrict__ ws)
{
  const int i = (blockIdx.x*256 + threadIdx.x)*4;   // 8 blocks * 256 * 4 = 8192
  float4 p4 = *(const float4*)(P + i);
  union { bf16x4 v; short s[4]; } u;
  u.s[0]=f2bf(p4.x); u.s[1]=f2bf(p4.y); u.s[2]=f2bf(p4.z); u.s[3]=f2bf(p4.w);
  *(bf16x4*)(ws + P_OFF + i) = u.v;
}

// ---------------- k1: per-chunk everything except cross-chunk prefix --------
__global__ __launch_bounds__(256) void k1(
    const float* __restrict__ qq, const float* __restrict__ kk,
    const float* __restrict__ vv, unsigned short* __restrict__ ws)
{
  __shared__ short Vt[64*VT_S];       // [d][t]
  __shared__ short Kft[128*KFT_S];    // [m][t]
  __shared__ short KfTM[64*TM_S];     // [t][m]
  __shared__ short QfTM[64*TM_S];     // [t][m]; reused as Sm after sync2

  const int tid = threadIdx.x, bid = blockIdx.x;
  const int bh = bid >> 6, c = bid & 63;
  const int b = bh >> 3, h = bh & 7;
  const int lane = tid & 63, w = tid >> 6, quad = lane >> 4, l15 = lane & 15;
  const size_t gbase = (size_t)b*LHD_ + (size_t)h*D_;
  const int t0 = c*T_;
  const unsigned short* Pb = ws + P_OFF;

  // stage Vt[d][t] (transpose)
  for (int fi = tid; fi < 64*16; fi += 256) {
    int t = fi >> 4, d4 = (fi & 15)*4;
    float4 v4 = *(const float4*)(vv + gbase + (size_t)(t0+t)*HD_ + d4);
    Vt[(d4+0)*VT_S + t] = f2bf(v4.x);
    Vt[(d4+1)*VT_S + t] = f2bf(v4.y);
    Vt[(d4+2)*VT_S + t] = f2bf(v4.z);
    Vt[(d4+3)*VT_S + t] = f2bf(v4.w);
  }

  // features, swapped operands: D[m][t] -> lane holds t=16w+l15, m=16ct+4q+reg
  const float* qrow = qq + gbase + (size_t)(t0 + 16*w + l15)*HD_;
  const float* krow = kk + gbase + (size_t)(t0 + 16*w + l15)*HD_;
  bf16x8 bq0 = load_cvt8(qrow + quad*8);
  bf16x8 bq1 = load_cvt8(qrow + 32 + quad*8);
  bf16x8 bk0 = load_cvt8(krow + quad*8);
  bf16x8 bk1 = load_cvt8(krow + 32 + quad*8);
  #pragma unroll
  for (int ct = 0; ct < 8; ++ct) {
    bf16x8 ap0 = *(const bf16x8*)(Pb + (ct*16 + l15)*64 + quad*8);
    bf16x8 ap1 = *(const bf16x8*)(Pb + (ct*16 + l15)*64 + 32 + quad*8);
    f32x4 qa = {0.f,0.f,0.f,0.f}, ka = {0.f,0.f,0.f,0.f};
    qa = MFMA(ap0,bq0,qa); qa = MFMA(ap1,bq1,qa);
    ka = MFMA(ap0,bk0,ka); ka = MFMA(ap1,bk1,ka);
    union { bf16x4 v; short s[4]; } pq, pk;
    #pragma unroll
    for (int reg = 0; reg < 4; ++reg) {
      int m = 16*ct + 4*quad + reg;
      short qv = f2bf(fmaxf(qa[reg]*RATIO, 0.f) + EPS);
      short kv = f2bf(fmaxf(ka[reg]*RATIO, 0.f) + EPS);
      pq.s[reg] = qv; pk.s[reg] = kv;
      Kft[m*KFT_S + 16*w + l15] = kv;
    }
    *(bf16x4*)&QfTM[(16*w+l15)*TM_S + 16*ct + 4*quad] = pq.v;
    *(bf16x4*)&KfTM[(16*w+l15)*TM_S + 16*ct + 4*quad] = pk.v;
  }
  __syncthreads();  // sync1: Vt, Kft, KfTM, QfTM complete

  unsigned short* csb = ws + (size_t)(bh*C_+c)*REC_CS;
  unsigned short* qfb = ws + QF_OFF + (size_t)(bh*C_+c)*REC_F;

  // copy out Qf [t][m] dense; fully coalesced 16B stores (1KB/wave)
  {
    int tt = tid >> 4, mb = (tid & 15)*8;
    #pragma unroll
    for (int j = 0; j < 4; ++j) {
      bf16x8 v8 = *(const bf16x8*)&QfTM[(tt + 16*j)*TM_S + mb];
      *(bf16x8*)(qfb + (tt + 16*j)*128 + mb) = v8;
    }
  }
  // Qf A-frags (rows 16w+l15) for S
  bf16x8 qfr[4];
  #pragma unroll
  for (int ks2 = 0; ks2 < 4; ++ks2)
    qfr[ks2] = *(const bf16x8*)&QfTM[(16*w+l15)*TM_S + ks2*32 + quad*8];

  // ks[m] = sum_t Kf[t][m]
  if (tid < 128) {
    float s = 0.f;
    #pragma unroll
    for (int i = 0; i < 8; ++i) {
      bf16x8 r = *(const bf16x8*)&Kft[tid*KFT_S + 8*i];
      #pragma unroll
      for (int j = 0; j < 8; ++j) s += bf2f(r[j]);
    }
    csb[64*128 + tid] = (unsigned short)f2bf(s);
  }

  // KV^T: cs[d][m] = sum_t Kf[t][m] V[t][d]; swapped -> D[m][d], 8B stores
  {
    bf16x8 av0 = *(const bf16x8*)&Vt[(16*w + l15)*VT_S + quad*8];
    bf16x8 av1 = *(const bf16x8*)&Vt[(16*w + l15)*VT_S + 32 + quad*8];
    #pragma unroll
    for (int mt = 0; mt < 8; ++mt) {
      bf16x8 b0 = *(const bf16x8*)&Kft[(16*mt + l15)*KFT_S + quad*8];
      bf16x8 b1 = *(const bf16x8*)&Kft[(16*mt + l15)*KFT_S + 32 + quad*8];
      f32x4 acc = {0.f,0.f,0.f,0.f};
      acc = MFMA(b0, av0, acc);
      acc = MFMA(b1, av1, acc);
      union { bf16x4 v; short s[4]; } pc;
      #pragma unroll
      for (int reg = 0; reg < 4; ++reg) pc.s[reg] = f2bf(acc[reg]);
      *(bf16x4*)(csb + (16*w + l15)*128 + 16*mt + 4*quad) = pc.v;
    }
  }
  __syncthreads();  // sync2: all QfTM reads done -> reuse as Sm

  short* Sm = QfTM;

  // S = mask(Qf Kf^T): D[t][j], A=Qf regs, B=KfTM rows
  f32x4 sacc[4];
  #pragma unroll
  for (int jt = 0; jt < 4; ++jt) { f32x4 z = {0.f,0.f,0.f,0.f}; sacc[jt] = z; }
  #pragma unroll
  for (int ks2 = 0; ks2 < 4; ++ks2) {
    #pragma unroll
    for (int jt = 0; jt < 4; ++jt) {
      bf16x8 bb = *(const bf16x8*)&KfTM[(16*jt + l15)*TM_S + ks2*32 + quad*8];
      sacc[jt] = MFMA(qfr[ks2], bb, sacc[jt]);
    }
  }
  float rs[4] = {0.f,0.f,0.f,0.f};
  #pragma unroll
  for (int jt = 0; jt < 4; ++jt)
    #pragma unroll
    for (int reg = 0; reg < 4; ++reg) {
      int row = 16*w + 4*quad + reg;
      int j = l15 + 16*jt;
      float val = (j <= row) ? sacc[jt][reg] : 0.f;
      rs[reg] += val;
      Sm[row*TM_S + j] = f2bf(val);
    }
  #pragma unroll
  for (int reg = 0; reg < 4; ++reg) {
    rs[reg] += __shfl_xor(rs[reg], 1);
    rs[reg] += __shfl_xor(rs[reg], 2);
    rs[reg] += __shfl_xor(rs[reg], 4);
    rs[reg] += __shfl_xor(rs[reg], 8);
  }
  float* rsg = (float*)(ws + RS_OFF);
  if (l15 < 4) {
    float v = (l15==0) ? rs[0] : (l15==1) ? rs[1] : (l15==2) ? rs[2] : rs[3];
    rsg[bh*L_ + t0 + 16*w + 4*quad + l15] = v;
  }

  // num2[t][d] = S V as D[d][t]: A=Vt rows d, B=Sm rows t (same-wave rows)
  float* n2 = (float*)(ws + N2_OFF);
  f32x4 nacc[4];
  #pragma unroll
  for (int ct = 0; ct < 4; ++ct) { f32x4 z = {0.f,0.f,0.f,0.f}; nacc[ct] = z; }
  #pragma unroll
  for (int kss = 0; kss < 2; ++kss) {
    bf16x8 sb = *(const bf16x8*)&Sm[(16*w + l15)*TM_S + kss*32 + quad*8];
    #pragma unroll
    for (int ct = 0; ct < 4; ++ct) {
      bf16x8 a = *(const bf16x8*)&Vt[(16*ct + l15)*VT_S + kss*32 + quad*8];
      nacc[ct] = MFMA(a, sb, nacc[ct]);
    }
  }
  const int tg = t0 + 16*w + l15;
  #pragma unroll
  for (int ct = 0; ct < 4; ++ct) {
    float4 o;
    o.x = nacc[ct][0]; o.y = nacc[ct][1]; o.z = nacc[ct][2]; o.w = nacc[ct][3];
    *(float4*)(n2 + gbase + (size_t)tg*HD_ + 16*ct + 4*quad) = o;
  }
}

// ---------------- k2: bf16 exclusive prefix, width-1, full prefetch ---------
__global__ __launch_bounds__(256) void k2(unsigned short* __restrict__ ws)
{
  const int gid = blockIdx.x*256 + threadIdx.x;   // 520*256 = 16*8320 exactly
  const int bh = gid / REC_CS, e = gid % REC_CS;
  unsigned short* base = ws + (size_t)bh*C_*REC_CS + e;
  short v[64];
  #pragma unroll
  for (int c2 = 0; c2 < 64; ++c2) v[c2] = (short)base[(size_t)c2*REC_CS];
  float run = 0.f;
  #pragma unroll
  for (int c2 = 0; c2 < 64; ++c2) {
    base[(size_t)c2*REC_CS] = (unsigned short)f2bf(run);
    run += bf2f(v[c2]);
  }
}

// ---------------- k3: num1 + combine, LDS-free, float4 stores ---------------
__global__ __launch_bounds__(256) void k3(
    const unsigned short* __restrict__ ws, float* __restrict__ out)
{
  const int tid = threadIdx.x, bid = blockIdx.x;
  const int bh = bid >> 6, c = bid & 63;
  const int b = bh >> 3, h = bh & 7;
  const int lane = tid & 63, w = tid >> 6, quad = lane >> 4, l15 = lane & 15;
  const size_t gbase = (size_t)b*LHD_ + (size_t)h*D_;
  const int t0 = c*T_;
  const unsigned short* csb = ws + (size_t)(bh*C_+c)*REC_CS;
  const unsigned short* qfb = ws + QF_OFF + (size_t)(bh*C_+c)*REC_F;
  const float* n2 = (const float*)(ws + N2_OFF);
  const float* rsg = (const float*)(ws + RS_OFF);

  const int tg = t0 + 16*w + l15;

  // hoist n2 + rs loads to overlap with MFMA latency
  float4 nv[4];
  #pragma unroll
  for (int ct = 0; ct < 4; ++ct)
    nv[ct] = *(const float4*)(n2 + gbase + (size_t)tg*HD_ + 16*ct + 4*quad);
  float rsv = rsg[bh*L_ + tg];

  // Qf B-frags (rows t=16w+l15) + prefixed ks frags
  bf16x8 qfB[4], ksf[4];
  #pragma unroll
  for (int ks2 = 0; ks2 < 4; ++ks2) {
    qfB[ks2] = *(const bf16x8*)(qfb + (16*w + l15)*128 + ks2*32 + quad*8);
    ksf[ks2] = *(const bf16x8*)(csb + 64*128 + ks2*32 + quad*8);
  }
  // den1 = Qf . ks_prefix (per-lane partial over 32 m, reduce across quads)
  float dp = 0.f;
  #pragma unroll
  for (int ks2 = 0; ks2 < 4; ++ks2)
    #pragma unroll
    for (int j = 0; j < 8; ++j) dp += bf2f(qfB[ks2][j]) * bf2f(ksf[ks2][j]);
  dp += __shfl_xor(dp, 16);
  dp += __shfl_xor(dp, 32);
  float inv = 1.f / (dp + rsv);

  // num1 = Qf * KVpre as D[d][t]: A=cs rows d, B=Qf rows t
  f32x4 nacc[4];
  #pragma unroll
  for (int ct = 0; ct < 4; ++ct) { f32x4 z = {0.f,0.f,0.f,0.f}; nacc[ct] = z; }
  #pragma unroll
  for (int ks2 = 0; ks2 < 4; ++ks2) {
    #pragma unroll
    for (int ct = 0; ct < 4; ++ct) {
      bf16x8 a = *(const bf16x8*)(csb + (16*ct + l15)*128 + ks2*32 + quad*8);
      nacc[ct] = MFMA(a, qfB[ks2], nacc[ct]);
    }
  }
  #pragma unroll
  for (int ct = 0; ct < 4; ++ct) {
    float4 o;
    o.x = (nacc[ct][0] + nv[ct].x) * inv;
    o.y = (nacc[ct][1] + nv[ct].y) * inv;
    o.z = (nacc[ct][2] + nv[ct].z) * inv;
    o.w = (nacc[ct][3] + nv[ct].w) * inv;
    *(float4*)(out + gbase + (size_t)tg*HD_ + 16*ct + 4*quad) = o;
  }
}

extern "C" void kernel_launch(void* const* d_in, const int* in_sizes, int n_in,
                              void* d_out, int out_size, void* d_ws, size_t ws_size,
                              hipStream_t stream) {
  const float* q = (const float*)d_in[0];
  const float* k = (const float*)d_in[1];
  const float* v = (const float*)d_in[2];
  const float* P = (const float*)d_in[3];
  float* out = (float*)d_out;
  unsigned short* ws = (unsigned short*)d_ws;  // needs ~48.6 MB

  dim3 blk(256);
  k0<<<dim3(8), blk, 0, stream>>>(P, ws);
  k1<<<dim3(BH_*C_), blk, 0, stream>>>(q, k, v, ws);
  k2<<<dim3(520), blk, 0, stream>>>(ws);
  k3<<<dim3(BH_*C_), blk, 0, stream>>>(ws, out);
}